// Round 1
// baseline (139.953 us; speedup 1.0000x reference)
//
#include <hip/hip_runtime.h>
#include <math.h>

#define B 16
#define N 200
#define HID 64
#define NH 2
#define D 32
#define EPSF 1e-12f
#define LOG_EPSF 1e-24f

// 1/sqrt(32)
#define RSQRT_D 0.17677669529663687f

// ---------------- Kernel 1: projections + folded pos + order/dist scalars ----
// grid = B*N/4 blocks, 256 threads (4 rows per block, one wave per row)
__global__ __launch_bounds__(256) void k_proj(
    const float* __restrict__ x,       // [B*N, HID]
    const float* __restrict__ pk,      // absolute_pos_K [B*N, HID]
    const float* __restrict__ pv,      // absolute_pos_V
    const float* __restrict__ Wq, const float* __restrict__ bq,
    const float* __restrict__ Wk, const float* __restrict__ bk,
    const float* __restrict__ Wv, const float* __restrict__ bv,
    const float* __restrict__ order_w, const float* __restrict__ dist_w,
    float* __restrict__ q,             // [B*N, HID]
    float* __restrict__ kp,            // k + pk
    float* __restrict__ vp,            // v + pv
    float* __restrict__ qo, float* __restrict__ ko,   // [B*NH*N]
    float* __restrict__ qd, float* __restrict__ kd)
{
    __shared__ float sX[4][HID];
    const int tid = threadIdx.x;
    const int sub = tid >> 6;      // row within block
    const int o   = tid & 63;      // output channel (== lane)
    const int row = blockIdx.x * 4 + sub;        // [0, B*N)

    sX[sub][o] = x[row * HID + o];
    __syncthreads();

    float qv = bq[o], kv = bk[o], vv = bv[o];
    #pragma unroll 8
    for (int c = 0; c < HID; ++c) {
        const float xv = sX[sub][c];
        qv = fmaf(xv, Wq[o * HID + c], qv);
        kv = fmaf(xv, Wk[o * HID + c], kv);
        vv = fmaf(xv, Wv[o * HID + c], vv);
    }
    q [row * HID + o] = qv;
    kp[row * HID + o] = kv + pk[row * HID + o];
    vp[row * HID + o] = vv + pv[row * HID + o];

    // order / dist rank-1 scalars; lanes 0..31 = head 0, lanes 32..63 = head 1
    const int d = o & 31;
    float qov = qv * order_w[d];
    float kov = kv * order_w[D + d];
    float qdv = qv * dist_w[d];
    float kdv = kv * dist_w[D + d];
    #pragma unroll
    for (int m = 16; m >= 1; m >>= 1) {
        qov += __shfl_xor(qov, m);   // stays within 32-lane half for m<=16
        kov += __shfl_xor(kov, m);
        qdv += __shfl_xor(qdv, m);
        kdv += __shfl_xor(kdv, m);
    }
    if (d == 0) {
        const int bb = row / N;
        const int ii = row - bb * N;
        const int h  = o >> 5;
        const int idx = (bb * NH + h) * N + ii;
        qo[idx] = qov;  ko[idx] = kov;
        qd[idx] = qdv;  kd[idx] = kdv;
    }
}

// ---------------- Kernel 2: fused scores + softmax + context --------------
// grid = B*NH*N blocks (one per (b,h,i)), 256 threads
__global__ __launch_bounds__(256) void k_attn(
    const float* __restrict__ q, const float* __restrict__ kp,
    const float* __restrict__ vp,
    const float* __restrict__ tk,     // [B,N,N,HID]
    const float* __restrict__ tv,
    const float* __restrict__ amask,  // [B,1,N,N]
    const float* __restrict__ qo, const float* __restrict__ ko,
    const float* __restrict__ qd, const float* __restrict__ kd,
    const float* __restrict__ order_b, const float* __restrict__ dist_b,
    const float* __restrict__ scalar,
    float* __restrict__ ctx)          // [B*N, HID]
{
    __shared__ float sQ[D];
    __shared__ float sP[256];
    __shared__ float sRed[4];
    __shared__ float sPart[D][33];

    const int tid = threadIdx.x;
    const int bid = blockIdx.x;
    const int i  = bid % N;
    const int bh = bid / N;           // b*NH + h
    const int h  = bh & (NH - 1);
    const int b  = bh >> 1;           // NH == 2

    if (tid < D) sQ[tid] = q[((size_t)(b * N + i)) * HID + h * D + tid];
    __syncthreads();

    // ---- phase B: scores for j = tid ----
    float s = -INFINITY;
    const int j = tid;
    if (j < N) {
        const float4* q4  = (const float4*)sQ;
        const float4* kp4 = (const float4*)(kp + ((size_t)(b * N + j)) * HID + h * D);
        const float4* tk4 = (const float4*)(tk + (((size_t)b * N + i) * N + j) * HID + h * D);
        float acc = 0.0f;
        #pragma unroll
        for (int dd = 0; dd < 8; ++dd) {
            const float4 a = q4[dd];
            const float4 k = kp4[dd];
            const float4 t = tk4[dd];
            acc += a.x * (k.x + t.x) + a.y * (k.y + t.y)
                 + a.z * (k.z + t.z) + a.w * (k.w + t.w);
        }
        // order (BCE-style) term
        const float lo = qo[bh * N + i] + ko[bh * N + j] + order_b[0];
        const float pr = 1.0f / (1.0f + expf(-lo));
        const float eo = (j > i) ? logf(pr + LOG_EPSF) : logf(1.0f - pr + LOG_EPSF);
        // distance term
        const float pd = qd[bh * N + i] + kd[bh * N + j] + dist_b[0];
        const float gd = logf(fabsf((float)(j - i)) + 1.0f);
        const float sc = scalar[0];
        const float dv = gd - pd;
        const float ed = -0.5f * dv * dv * sc * sc;

        s = (acc + eo + ed) * RSQRT_D + amask[((size_t)b * N + i) * N + j];
    }

    // ---- softmax over j ----
    float m = s;
    #pragma unroll
    for (int k = 32; k >= 1; k >>= 1) m = fmaxf(m, __shfl_xor(m, k));
    if ((tid & 63) == 0) sRed[tid >> 6] = m;
    __syncthreads();
    m = fmaxf(fmaxf(sRed[0], sRed[1]), fmaxf(sRed[2], sRed[3]));
    __syncthreads();

    const float e = (j < N) ? expf(s - m) : 0.0f;
    float t = e;
    #pragma unroll
    for (int k = 32; k >= 1; k >>= 1) t += __shfl_xor(t, k);
    if ((tid & 63) == 0) sRed[tid >> 6] = t;
    __syncthreads();
    const float tot = sRed[0] + sRed[1] + sRed[2] + sRed[3];
    sP[tid] = e * (1.0f / tot);
    __syncthreads();

    // ---- phase C: ctx_d = sum_j p_j * (vp[j,d] + tv[i,j,d]) ----
    const int c4 = tid & 7;          // which float4 of the 32-float head slice
    const int jc = tid >> 3;         // 0..31
    float4 acc4 = make_float4(0.f, 0.f, 0.f, 0.f);
    for (int jj = jc; jj < N; jj += 32) {
        const float p = sP[jj];
        const float4 vv = ((const float4*)(vp + ((size_t)(b * N + jj)) * HID + h * D))[c4];
        const float4 tt = ((const float4*)(tv + (((size_t)b * N + i) * N + jj) * HID + h * D))[c4];
        acc4.x += p * (vv.x + tt.x);
        acc4.y += p * (vv.y + tt.y);
        acc4.z += p * (vv.z + tt.z);
        acc4.w += p * (vv.w + tt.w);
    }
    sPart[c4 * 4 + 0][jc] = acc4.x;
    sPart[c4 * 4 + 1][jc] = acc4.y;
    sPart[c4 * 4 + 2][jc] = acc4.z;
    sPart[c4 * 4 + 3][jc] = acc4.w;
    __syncthreads();
    if (tid < D) {
        float sum = 0.0f;
        #pragma unroll
        for (int g = 0; g < 32; ++g) sum += sPart[tid][g];
        ctx[((size_t)(b * N + i)) * HID + h * D + tid] = sum;
    }
}

// ---------------- Kernel 3: output proj + residual + LayerNorm ------------
__global__ __launch_bounds__(256) void k_out(
    const float* __restrict__ ctx, const float* __restrict__ x,
    const float* __restrict__ Wd, const float* __restrict__ bd,
    const float* __restrict__ ln_g, const float* __restrict__ ln_b,
    float* __restrict__ out)
{
    __shared__ float sC[4][HID];
    const int tid = threadIdx.x;
    const int sub = tid >> 6;
    const int o   = tid & 63;
    const int row = blockIdx.x * 4 + sub;

    sC[sub][o] = ctx[row * HID + o];
    __syncthreads();

    float hv = bd[o] + x[row * HID + o];
    #pragma unroll 8
    for (int c = 0; c < HID; ++c)
        hv = fmaf(sC[sub][c], Wd[o * HID + c], hv);

    float sum = hv;
    #pragma unroll
    for (int m = 32; m >= 1; m >>= 1) sum += __shfl_xor(sum, m);
    const float mu = sum * (1.0f / 64.0f);
    const float dv = hv - mu;
    float vs = dv * dv;
    #pragma unroll
    for (int m = 32; m >= 1; m >>= 1) vs += __shfl_xor(vs, m);
    const float var = vs * (1.0f / 64.0f);

    out[row * HID + o] = dv * rsqrtf(var + EPSF) * ln_g[o] + ln_b[o];
}

extern "C" void kernel_launch(void* const* d_in, const int* in_sizes, int n_in,
                              void* d_out, int out_size, void* d_ws, size_t ws_size,
                              hipStream_t stream) {
    const float* x     = (const float*)d_in[0];
    const float* amask = (const float*)d_in[1];
    const float* apk   = (const float*)d_in[2];
    const float* apv   = (const float*)d_in[3];
    const float* tk    = (const float*)d_in[4];
    const float* tv    = (const float*)d_in[5];
    const float* Wq    = (const float*)d_in[6];
    const float* bq    = (const float*)d_in[7];
    const float* Wk    = (const float*)d_in[8];
    const float* bk    = (const float*)d_in[9];
    const float* Wv    = (const float*)d_in[10];
    const float* bv    = (const float*)d_in[11];
    const float* Wd    = (const float*)d_in[12];
    const float* bd    = (const float*)d_in[13];
    const float* order_w = (const float*)d_in[14];
    const float* order_b = (const float*)d_in[15];
    const float* dist_w  = (const float*)d_in[16];
    const float* dist_b  = (const float*)d_in[17];
    const float* scalar  = (const float*)d_in[18];
    const float* ln_g    = (const float*)d_in[19];
    const float* ln_b    = (const float*)d_in[20];

    float* ws = (float*)d_ws;
    const size_t nrow = (size_t)B * N * HID;       // 819200
    float* qbuf  = ws;
    float* kpbuf = ws + nrow;
    float* vpbuf = ws + 2 * nrow;
    float* ctxb  = ws + 3 * nrow;
    float* qob   = ws + 4 * nrow;
    float* kob   = qob + (size_t)B * NH * N;
    float* qdb   = kob + (size_t)B * NH * N;
    float* kdb   = qdb + (size_t)B * NH * N;

    k_proj<<<(B * N) / 4, 256, 0, stream>>>(x, apk, apv, Wq, bq, Wk, bk, Wv, bv,
                                            order_w, dist_w,
                                            qbuf, kpbuf, vpbuf, qob, kob, qdb, kdb);

    k_attn<<<B * NH * N, 256, 0, stream>>>(qbuf, kpbuf, vpbuf, tk, tv, amask,
                                           qob, kob, qdb, kdb,
                                           order_b, dist_b, scalar, ctxb);

    k_out<<<(B * N) / 4, 256, 0, stream>>>(ctxb, x, Wd, bd, ln_g, ln_b,
                                           (float*)d_out);
}

// Round 2
// 114.659 us; speedup vs baseline: 1.2206x; 1.2206x over previous
//
#include <hip/hip_runtime.h>
#include <math.h>

#define B 16
#define N 200
#define HID 64
#define NH 2
#define D 32
#define EPSF 1e-12f
#define LOG_EPSF 1e-24f

// 1/sqrt(32)
#define RSQRT_D 0.17677669529663687f

// ---------------- Kernel 1: projections + folded pos + order/dist scalars ----
// grid = B*N/4 blocks, 256 threads (4 rows per block, one wave per row)
__global__ __launch_bounds__(256) void k_proj(
    const float* __restrict__ x,       // [B*N, HID]
    const float* __restrict__ pk,      // absolute_pos_K [B*N, HID]
    const float* __restrict__ pv,      // absolute_pos_V
    const float* __restrict__ Wq, const float* __restrict__ bq,
    const float* __restrict__ Wk, const float* __restrict__ bk,
    const float* __restrict__ Wv, const float* __restrict__ bv,
    const float* __restrict__ order_w, const float* __restrict__ dist_w,
    float* __restrict__ q,             // [B*N, HID]
    float* __restrict__ kp,            // k + pk
    float* __restrict__ vp,            // v + pv
    float* __restrict__ qo, float* __restrict__ ko,   // [B*NH*N]
    float* __restrict__ qd, float* __restrict__ kd)
{
    __shared__ float sX[4][HID];
    const int tid = threadIdx.x;
    const int sub = tid >> 6;      // row within block
    const int o   = tid & 63;      // output channel (== lane)
    const int row = blockIdx.x * 4 + sub;        // [0, B*N)

    sX[sub][o] = x[row * HID + o];
    __syncthreads();

    float qv = bq[o], kv = bk[o], vv = bv[o];
    #pragma unroll 8
    for (int c = 0; c < HID; ++c) {
        const float xv = sX[sub][c];
        qv = fmaf(xv, Wq[o * HID + c], qv);
        kv = fmaf(xv, Wk[o * HID + c], kv);
        vv = fmaf(xv, Wv[o * HID + c], vv);
    }
    q [row * HID + o] = qv;
    kp[row * HID + o] = kv + pk[row * HID + o];
    vp[row * HID + o] = vv + pv[row * HID + o];

    // order / dist rank-1 scalars; lanes 0..31 = head 0, lanes 32..63 = head 1
    const int d = o & 31;
    float qov = qv * order_w[d];
    float kov = kv * order_w[D + d];
    float qdv = qv * dist_w[d];
    float kdv = kv * dist_w[D + d];
    #pragma unroll
    for (int m = 16; m >= 1; m >>= 1) {
        qov += __shfl_xor(qov, m);   // stays within 32-lane half for m<=16
        kov += __shfl_xor(kov, m);
        qdv += __shfl_xor(qdv, m);
        kdv += __shfl_xor(kdv, m);
    }
    if (d == 0) {
        const int bb = row / N;
        const int ii = row - bb * N;
        const int h  = o >> 5;
        const int idx = (bb * NH + h) * N + ii;
        qo[idx] = qov;  ko[idx] = kov;
        qd[idx] = qdv;  kd[idx] = kdv;
    }
}

// ---------------- Kernel 2: fused scores + softmax + context --------------
// grid = B*N blocks (one per (b,i)), 128 threads = 2 waves = the 2 heads.
// Zero __syncthreads: each wave is fully independent; LDS ordering within a
// wave is enforced with s_waitcnt lgkmcnt(0).
// Lane layout: lane = 8*g + c ; g = j-subgroup (0..7), c = float4 column (0..7).
// Every global load instruction covers 8 dense 128-byte segments.
__global__ __launch_bounds__(128) void k_attn(
    const float* __restrict__ q, const float* __restrict__ kp,
    const float* __restrict__ vp,
    const float* __restrict__ tk,     // [B,N,N,HID]
    const float* __restrict__ tv,
    const float* __restrict__ amask,  // [B,1,N,N]
    const float* __restrict__ qo, const float* __restrict__ ko,
    const float* __restrict__ qd, const float* __restrict__ kd,
    const float* __restrict__ order_b, const float* __restrict__ dist_b,
    const float* __restrict__ scalar,
    float* __restrict__ ctx)          // [B*N, HID]
{
    __shared__ float sS[2][256];      // per-head score/prob row

    const int tid  = threadIdx.x;
    const int h    = tid >> 6;        // head
    const int lane = tid & 63;
    const int g    = lane >> 3;       // j subgroup 0..7
    const int c    = lane & 7;        // float4 column 0..7
    const int bi   = blockIdx.x;      // b*N + i
    const int b    = bi / N;
    const int i    = bi - b * N;
    const int bh   = b * NH + h;

    float* S = sS[h];

    // per-lane q fragment (4 dims)
    const float4 qf = ((const float4*)(q + (size_t)bi * HID + h * D))[c];

    // wave-uniform scalars
    const float qoi = qo[bh * N + i];
    const float qdi = qd[bh * N + i];
    const float ob  = order_b[0];
    const float db  = dist_b[0];
    const float sc  = scalar[0];
    const float sc2h = 0.5f * sc * sc;

    const float* kpb = kp + (size_t)b * N * HID + h * D;          // + j*HID
    const float* tkb = tk + (size_t)bi * N * HID + h * D;         // + j*HID
    const float* vpb = vp + (size_t)b * N * HID + h * D;
    const float* tvb = tv + (size_t)bi * N * HID + h * D;
    const float* mb  = amask + (size_t)bi * N;                    // + j
    const float* kob = ko + (size_t)bh * N;
    const float* kdb = kd + (size_t)bh * N;

    // ---- phase B: scores ----
    #pragma unroll 5
    for (int it = 0; it < 25; ++it) {
        const int j = it * 8 + g;
        const float4 kv  = ((const float4*)(kpb + (size_t)j * HID))[c];
        const float4 tkv = ((const float4*)(tkb + (size_t)j * HID))[c];
        float part = qf.x * (kv.x + tkv.x) + qf.y * (kv.y + tkv.y)
                   + qf.z * (kv.z + tkv.z) + qf.w * (kv.w + tkv.w);
        part += __shfl_xor(part, 1);
        part += __shfl_xor(part, 2);
        part += __shfl_xor(part, 4);   // all 8 lanes of the group hold the dot

        const float lo = qoi + kob[j] + ob;
        const float pr = 1.0f / (1.0f + expf(-lo));
        const float eo = (j > i) ? logf(pr + LOG_EPSF) : logf(1.0f - pr + LOG_EPSF);
        const float pd = qdi + kdb[j] + db;
        const float gd = logf((float)(j > i ? j - i : i - j) + 1.0f);
        const float dv = gd - pd;
        const float ed = -sc2h * dv * dv;

        const float sj = (part + eo + ed) * RSQRT_D + mb[j];
        if (c == 0) S[j] = sj;
    }
    asm volatile("s_waitcnt lgkmcnt(0)" ::: "memory");

    // ---- softmax over 200 (within wave, shuffle reductions) ----
    const float s0 = S[lane];
    const float s1 = S[lane + 64];
    const float s2 = S[lane + 128];
    const float s3 = (lane < 8) ? S[lane + 192] : -INFINITY;
    float m = fmaxf(fmaxf(s0, s1), fmaxf(s2, s3));
    #pragma unroll
    for (int k = 32; k >= 1; k >>= 1) m = fmaxf(m, __shfl_xor(m, k));
    const float e0 = expf(s0 - m);
    const float e1 = expf(s1 - m);
    const float e2 = expf(s2 - m);
    const float e3 = (lane < 8) ? expf(s3 - m) : 0.0f;
    float t = e0 + e1 + e2 + e3;
    #pragma unroll
    for (int k = 32; k >= 1; k >>= 1) t += __shfl_xor(t, k);
    const float rinv = 1.0f / t;
    S[lane]       = e0 * rinv;
    S[lane + 64]  = e1 * rinv;
    S[lane + 128] = e2 * rinv;
    if (lane < 8) S[lane + 192] = e3 * rinv;
    asm volatile("s_waitcnt lgkmcnt(0)" ::: "memory");

    // ---- phase C: ctx = sum_j p_j * (vp[j] + tv[i,j]) ----
    float4 r = make_float4(0.f, 0.f, 0.f, 0.f);
    #pragma unroll 5
    for (int it = 0; it < 25; ++it) {
        const int j = it * 8 + g;
        const float p = S[j];
        const float4 vv  = ((const float4*)(vpb + (size_t)j * HID))[c];
        const float4 tvv = ((const float4*)(tvb + (size_t)j * HID))[c];
        r.x += p * (vv.x + tvv.x);
        r.y += p * (vv.y + tvv.y);
        r.z += p * (vv.z + tvv.z);
        r.w += p * (vv.w + tvv.w);
    }
    // reduce across the 8 j-subgroups (lanes sharing c): masks 8,16,32
    #pragma unroll
    for (int k = 8; k <= 32; k <<= 1) {
        r.x += __shfl_xor(r.x, k);
        r.y += __shfl_xor(r.y, k);
        r.z += __shfl_xor(r.z, k);
        r.w += __shfl_xor(r.w, k);
    }
    if (g == 0)
        ((float4*)(ctx + (size_t)bi * HID + h * D))[c] = r;
}

// ---------------- Kernel 3: output proj + residual + LayerNorm ------------
__global__ __launch_bounds__(256) void k_out(
    const float* __restrict__ ctx, const float* __restrict__ x,
    const float* __restrict__ Wd, const float* __restrict__ bd,
    const float* __restrict__ ln_g, const float* __restrict__ ln_b,
    float* __restrict__ out)
{
    __shared__ float sC[4][HID];
    const int tid = threadIdx.x;
    const int sub = tid >> 6;
    const int o   = tid & 63;
    const int row = blockIdx.x * 4 + sub;

    sC[sub][o] = ctx[row * HID + o];
    __syncthreads();

    float hv = bd[o] + x[row * HID + o];
    #pragma unroll 8
    for (int c = 0; c < HID; ++c)
        hv = fmaf(sC[sub][c], Wd[o * HID + c], hv);

    float sum = hv;
    #pragma unroll
    for (int m = 32; m >= 1; m >>= 1) sum += __shfl_xor(sum, m);
    const float mu = sum * (1.0f / 64.0f);
    const float dv = hv - mu;
    float vs = dv * dv;
    #pragma unroll
    for (int m = 32; m >= 1; m >>= 1) vs += __shfl_xor(vs, m);
    const float var = vs * (1.0f / 64.0f);

    out[row * HID + o] = dv * rsqrtf(var + EPSF) * ln_g[o] + ln_b[o];
}

extern "C" void kernel_launch(void* const* d_in, const int* in_sizes, int n_in,
                              void* d_out, int out_size, void* d_ws, size_t ws_size,
                              hipStream_t stream) {
    const float* x     = (const float*)d_in[0];
    const float* amask = (const float*)d_in[1];
    const float* apk   = (const float*)d_in[2];
    const float* apv   = (const float*)d_in[3];
    const float* tk    = (const float*)d_in[4];
    const float* tv    = (const float*)d_in[5];
    const float* Wq    = (const float*)d_in[6];
    const float* bq    = (const float*)d_in[7];
    const float* Wk    = (const float*)d_in[8];
    const float* bk    = (const float*)d_in[9];
    const float* Wv    = (const float*)d_in[10];
    const float* bv    = (const float*)d_in[11];
    const float* Wd    = (const float*)d_in[12];
    const float* bd    = (const float*)d_in[13];
    const float* order_w = (const float*)d_in[14];
    const float* order_b = (const float*)d_in[15];
    const float* dist_w  = (const float*)d_in[16];
    const float* dist_b  = (const float*)d_in[17];
    const float* scalar  = (const float*)d_in[18];
    const float* ln_g    = (const float*)d_in[19];
    const float* ln_b    = (const float*)d_in[20];

    float* ws = (float*)d_ws;
    const size_t nrow = (size_t)B * N * HID;       // 819200
    float* qbuf  = ws;
    float* kpbuf = ws + nrow;
    float* vpbuf = ws + 2 * nrow;
    float* ctxb  = ws + 3 * nrow;
    float* qob   = ws + 4 * nrow;
    float* kob   = qob + (size_t)B * NH * N;
    float* qdb   = kob + (size_t)B * NH * N;
    float* kdb   = qdb + (size_t)B * NH * N;

    k_proj<<<(B * N) / 4, 256, 0, stream>>>(x, apk, apv, Wq, bq, Wk, bk, Wv, bv,
                                            order_w, dist_w,
                                            qbuf, kpbuf, vpbuf, qob, kob, qdb, kdb);

    k_attn<<<B * N, 128, 0, stream>>>(qbuf, kpbuf, vpbuf, tk, tv, amask,
                                      qob, kob, qdb, kdb,
                                      order_b, dist_b, scalar, ctxb);

    k_out<<<(B * N) / 4, 256, 0, stream>>>(ctxb, x, Wd, bd, ln_g, ln_b,
                                           (float*)d_out);
}

// Round 3
// 106.913 us; speedup vs baseline: 1.3090x; 1.0725x over previous
//
#include <hip/hip_runtime.h>
#include <math.h>

#define B 16
#define N 200
#define HID 64
#define NH 2
#define D 32
#define EPSF 1e-12f
#define LOG_EPSF 1e-24f

// 1/sqrt(32)
#define RSQRT_D 0.17677669529663687f

// ---------------- Kernel 1: projections + folded pos + order/dist scalars ----
// grid = B*N/4 blocks, 256 threads (4 rows per block, one wave per row)
__global__ __launch_bounds__(256) void k_proj(
    const float* __restrict__ x,       // [B*N, HID]
    const float* __restrict__ pk,      // absolute_pos_K [B*N, HID]
    const float* __restrict__ pv,      // absolute_pos_V
    const float* __restrict__ Wq, const float* __restrict__ bq,
    const float* __restrict__ Wk, const float* __restrict__ bk,
    const float* __restrict__ Wv, const float* __restrict__ bv,
    const float* __restrict__ order_w, const float* __restrict__ dist_w,
    float* __restrict__ q,             // [B*N, HID]
    float* __restrict__ kp,            // k + pk
    float* __restrict__ vp,            // v + pv
    float* __restrict__ qo, float* __restrict__ ko,   // [B*NH*N]
    float* __restrict__ qd, float* __restrict__ kd)
{
    __shared__ float sX[4][HID];
    const int tid = threadIdx.x;
    const int sub = tid >> 6;      // row within block
    const int o   = tid & 63;      // output channel (== lane)
    const int row = blockIdx.x * 4 + sub;        // [0, B*N)

    sX[sub][o] = x[row * HID + o];
    __syncthreads();

    float qv = bq[o], kv = bk[o], vv = bv[o];
    #pragma unroll 8
    for (int c = 0; c < HID; ++c) {
        const float xv = sX[sub][c];
        qv = fmaf(xv, Wq[o * HID + c], qv);
        kv = fmaf(xv, Wk[o * HID + c], kv);
        vv = fmaf(xv, Wv[o * HID + c], vv);
    }
    q [row * HID + o] = qv;
    kp[row * HID + o] = kv + pk[row * HID + o];
    vp[row * HID + o] = vv + pv[row * HID + o];

    // order / dist rank-1 scalars; lanes 0..31 = head 0, lanes 32..63 = head 1
    const int d = o & 31;
    float qov = qv * order_w[d];
    float kov = kv * order_w[D + d];
    float qdv = qv * dist_w[d];
    float kdv = kv * dist_w[D + d];
    #pragma unroll
    for (int m = 16; m >= 1; m >>= 1) {
        qov += __shfl_xor(qov, m);   // stays within 32-lane half for m<=16
        kov += __shfl_xor(kov, m);
        qdv += __shfl_xor(qdv, m);
        kdv += __shfl_xor(kdv, m);
    }
    if (d == 0) {
        const int bb = row / N;
        const int ii = row - bb * N;
        const int h  = o >> 5;
        const int idx = (bb * NH + h) * N + ii;
        qo[idx] = qov;  ko[idx] = kov;
        qd[idx] = qdv;  kd[idx] = kdv;
    }
}

// ---------------- Kernel 2: fused scores + softmax + context --------------
// grid = B*NH*N blocks, 64 threads = ONE WAVE per (b,h,i). Zero barriers.
// Phase A: lane-owns-j computes the order/dist/mask additive term (all
//          transcendentals) ONCE per j, coalesced gathers -> S_aux LDS.
// Phase B: pure streaming: lane = 8*g + c; per iter 1 kp load (L2) + 1 tk
//          load (HBM), dot via 3 shuffles, partial score -> S_dot LDS.
// Softmax: combine S_aux + S_dot with wave shuffle reductions; P -> S_aux.
// Phase C: stream vp + tv weighted by P.
__global__ __launch_bounds__(64) void k_attn(
    const float* __restrict__ q, const float* __restrict__ kp,
    const float* __restrict__ vp,
    const float* __restrict__ tk,     // [B,N,N,HID]
    const float* __restrict__ tv,
    const float* __restrict__ amask,  // [B,1,N,N]
    const float* __restrict__ qo, const float* __restrict__ ko,
    const float* __restrict__ qd, const float* __restrict__ kd,
    const float* __restrict__ order_b, const float* __restrict__ dist_b,
    const float* __restrict__ scalar,
    float* __restrict__ ctx)          // [B*N, HID]
{
    __shared__ float S_aux[256];
    __shared__ float S_dot[256];

    const int lane = threadIdx.x;
    const int g    = lane >> 3;       // j subgroup 0..7
    const int c    = lane & 7;        // float4 column 0..7
    const int bid  = blockIdx.x;      // bh*N + i
    const int bh   = bid / N;
    const int i    = bid - bh * N;
    const int b    = bh >> 1;         // NH == 2
    const int h    = bh & 1;
    const int bi   = b * N + i;

    // per-lane q fragment (4 dims)
    const float4 qf = ((const float4*)(q + (size_t)bi * HID + h * D))[c];

    // wave-uniform scalars
    const float qoi = qo[bh * N + i];
    const float qdi = qd[bh * N + i];
    const float ob  = order_b[0];
    const float db  = dist_b[0];
    const float sc  = scalar[0];
    const float sc2h = 0.5f * sc * sc;

    const float* kpb = kp + (size_t)b * N * HID + h * D;          // + j*HID
    const float* tkb = tk + (size_t)bi * N * HID + h * D;         // + j*HID
    const float* vpb = vp + (size_t)b * N * HID + h * D;
    const float* tvb = tv + (size_t)bi * N * HID + h * D;
    const float* mb  = amask + (size_t)bi * N;                    // + j
    const float* kob = ko + (size_t)bh * N;
    const float* kdb = kd + (size_t)bh * N;

    // ---- phase A: additive aux term per j (transcendentals, once per j) ----
    #pragma unroll
    for (int r = 0; r < 4; ++r) {
        const int j = r * 64 + lane;
        if (j < N) {
            const float lo = qoi + kob[j] + ob;
            // j>i: log(sigmoid(lo)) = -log1p(exp(-lo)); else log(1-sigmoid(lo))
            const float xs = (j > i) ? -lo : lo;
            const float eo = -log1pf(expf(xs));
            const float pd = qdi + kdb[j] + db;
            const float gd = logf((float)(j > i ? j - i : i - j) + 1.0f);
            const float dv = gd - pd;
            S_aux[j] = (eo - sc2h * dv * dv) * RSQRT_D + mb[j];
        }
    }

    // ---- phase B: pure streaming dot products ----
    #pragma unroll 5
    for (int it = 0; it < 25; ++it) {
        const int j = it * 8 + g;
        const float4 kv  = ((const float4*)(kpb + (size_t)j * HID))[c];
        const float4 tkv = ((const float4*)(tkb + (size_t)j * HID))[c];
        float part = qf.x * (kv.x + tkv.x) + qf.y * (kv.y + tkv.y)
                   + qf.z * (kv.z + tkv.z) + qf.w * (kv.w + tkv.w);
        part += __shfl_xor(part, 1);
        part += __shfl_xor(part, 2);
        part += __shfl_xor(part, 4);
        if (c == 0) S_dot[j] = part * RSQRT_D;
    }
    asm volatile("s_waitcnt lgkmcnt(0)" ::: "memory");

    // ---- softmax over 200 (within wave, shuffle reductions) ----
    const float s0 = S_aux[lane]       + S_dot[lane];
    const float s1 = S_aux[lane + 64]  + S_dot[lane + 64];
    const float s2 = S_aux[lane + 128] + S_dot[lane + 128];
    const float s3 = (lane < 8) ? (S_aux[lane + 192] + S_dot[lane + 192]) : -INFINITY;
    float m = fmaxf(fmaxf(s0, s1), fmaxf(s2, s3));
    #pragma unroll
    for (int k = 32; k >= 1; k >>= 1) m = fmaxf(m, __shfl_xor(m, k));
    const float e0 = expf(s0 - m);
    const float e1 = expf(s1 - m);
    const float e2 = expf(s2 - m);
    const float e3 = (lane < 8) ? expf(s3 - m) : 0.0f;
    float t = e0 + e1 + e2 + e3;
    #pragma unroll
    for (int k = 32; k >= 1; k >>= 1) t += __shfl_xor(t, k);
    const float rinv = 1.0f / t;
    S_aux[lane]       = e0 * rinv;
    S_aux[lane + 64]  = e1 * rinv;
    S_aux[lane + 128] = e2 * rinv;
    if (lane < 8) S_aux[lane + 192] = e3 * rinv;
    asm volatile("s_waitcnt lgkmcnt(0)" ::: "memory");

    // ---- phase C: ctx = sum_j p_j * (vp[j] + tv[i,j]) ----
    float4 r4 = make_float4(0.f, 0.f, 0.f, 0.f);
    #pragma unroll 5
    for (int it = 0; it < 25; ++it) {
        const int j = it * 8 + g;
        const float p = S_aux[j];
        const float4 vv  = ((const float4*)(vpb + (size_t)j * HID))[c];
        const float4 tvv = ((const float4*)(tvb + (size_t)j * HID))[c];
        r4.x += p * (vv.x + tvv.x);
        r4.y += p * (vv.y + tvv.y);
        r4.z += p * (vv.z + tvv.z);
        r4.w += p * (vv.w + tvv.w);
    }
    // reduce across the 8 j-subgroups (lanes sharing c): masks 8,16,32
    #pragma unroll
    for (int k = 8; k <= 32; k <<= 1) {
        r4.x += __shfl_xor(r4.x, k);
        r4.y += __shfl_xor(r4.y, k);
        r4.z += __shfl_xor(r4.z, k);
        r4.w += __shfl_xor(r4.w, k);
    }
    if (g == 0)
        ((float4*)(ctx + (size_t)bi * HID + h * D))[c] = r4;
}

// ---------------- Kernel 3: output proj + residual + LayerNorm ------------
__global__ __launch_bounds__(256) void k_out(
    const float* __restrict__ ctx, const float* __restrict__ x,
    const float* __restrict__ Wd, const float* __restrict__ bd,
    const float* __restrict__ ln_g, const float* __restrict__ ln_b,
    float* __restrict__ out)
{
    __shared__ float sC[4][HID];
    const int tid = threadIdx.x;
    const int sub = tid >> 6;
    const int o   = tid & 63;
    const int row = blockIdx.x * 4 + sub;

    sC[sub][o] = ctx[row * HID + o];
    __syncthreads();

    float hv = bd[o] + x[row * HID + o];
    #pragma unroll 8
    for (int c = 0; c < HID; ++c)
        hv = fmaf(sC[sub][c], Wd[o * HID + c], hv);

    float sum = hv;
    #pragma unroll
    for (int m = 32; m >= 1; m >>= 1) sum += __shfl_xor(sum, m);
    const float mu = sum * (1.0f / 64.0f);
    const float dv = hv - mu;
    float vs = dv * dv;
    #pragma unroll
    for (int m = 32; m >= 1; m >>= 1) vs += __shfl_xor(vs, m);
    const float var = vs * (1.0f / 64.0f);

    out[row * HID + o] = dv * rsqrtf(var + EPSF) * ln_g[o] + ln_b[o];
}

extern "C" void kernel_launch(void* const* d_in, const int* in_sizes, int n_in,
                              void* d_out, int out_size, void* d_ws, size_t ws_size,
                              hipStream_t stream) {
    const float* x     = (const float*)d_in[0];
    const float* amask = (const float*)d_in[1];
    const float* apk   = (const float*)d_in[2];
    const float* apv   = (const float*)d_in[3];
    const float* tk    = (const float*)d_in[4];
    const float* tv    = (const float*)d_in[5];
    const float* Wq    = (const float*)d_in[6];
    const float* bq    = (const float*)d_in[7];
    const float* Wk    = (const float*)d_in[8];
    const float* bk    = (const float*)d_in[9];
    const float* Wv    = (const float*)d_in[10];
    const float* bv    = (const float*)d_in[11];
    const float* Wd    = (const float*)d_in[12];
    const float* bd    = (const float*)d_in[13];
    const float* order_w = (const float*)d_in[14];
    const float* order_b = (const float*)d_in[15];
    const float* dist_w  = (const float*)d_in[16];
    const float* dist_b  = (const float*)d_in[17];
    const float* scalar  = (const float*)d_in[18];
    const float* ln_g    = (const float*)d_in[19];
    const float* ln_b    = (const float*)d_in[20];

    float* ws = (float*)d_ws;
    const size_t nrow = (size_t)B * N * HID;       // 819200
    float* qbuf  = ws;
    float* kpbuf = ws + nrow;
    float* vpbuf = ws + 2 * nrow;
    float* ctxb  = ws + 3 * nrow;
    float* qob   = ws + 4 * nrow;
    float* kob   = qob + (size_t)B * NH * N;
    float* qdb   = kob + (size_t)B * NH * N;
    float* kdb   = qdb + (size_t)B * NH * N;

    k_proj<<<(B * N) / 4, 256, 0, stream>>>(x, apk, apv, Wq, bq, Wk, bk, Wv, bv,
                                            order_w, dist_w,
                                            qbuf, kpbuf, vpbuf, qob, kob, qdb, kdb);

    k_attn<<<B * NH * N, 64, 0, stream>>>(qbuf, kpbuf, vpbuf, tk, tv, amask,
                                          qob, kob, qdb, kdb,
                                          order_b, dist_b, scalar, ctxb);

    k_out<<<(B * N) / 4, 256, 0, stream>>>(ctxb, x, Wd, bd, ln_g, ln_b,
                                           (float*)d_out);
}